// Round 3
// baseline (6042.598 us; speedup 1.0000x reference)
//
#include <hip/hip_runtime.h>
#include <math.h>

#define T_TASKS 64
#define NS 75
#define NW 5
#define NTOT 375
#define NQ 150
#define DIM 4096
#define QP_ITERS 15
#define SIGMA 0.1f
#define CREG 0.1f

// workspace layout (float offsets). K is padded 76x76 per task (5776).
// W region (320*5776) is aliased by gram partials (4*369664) pre-loop and by
// vbuf (64*5*4096) post-loop. Total 2,318,784 floats = 9.3 MB.
#define OFF_K   0u          // 64*5776  = 369664
#define OFF_W   369664u     // 320*5776 = 1848320 (alias: Kp, vbuf)
#define OFF_Z   2217984u    // 24000
#define OFF_S   2241984u    // 24000
#define OFF_LAM 2265984u    // 24000
#define OFF_NU  2289984u    // 4800
#define OFF_TV  2294784u    // 24000  -> end 2318784

// ---------------------------------------------------------------- init state
__global__ void qp_init(float* __restrict__ z, float* __restrict__ s,
                        float* __restrict__ lam, float* __restrict__ nu) {
    int idx = blockIdx.x * 256 + threadIdx.x;
    if (idx < T_TASKS * NTOT) { z[idx] = 0.f; s[idx] = 1.f; lam[idx] = 1.f; }
    if (idx < T_TASKS * NS) nu[idx] = 0.f;
}

// ------------------------------------------- K partial over a d-quarter.
// grid (4 quarters, 64 tasks), block 256 (16x16 threads, 5x5 tile each,
// covering 80x80; rows/cols >=75 guarded). 128-d staging chunks.
__global__ __launch_bounds__(256) void gram_partial(const float* __restrict__ support,
                                                    float* __restrict__ Kp) {
    int qd = blockIdx.x, b = blockIdx.y;
    __shared__ __align__(16) float Ss[80 * 132];
    int tid = threadIdx.x;
    int tx = tid & 15, ty = tid >> 4;
    float acc[5][5];
#pragma unroll
    for (int u = 0; u < 5; u++)
#pragma unroll
        for (int v = 0; v < 5; v++) acc[u][v] = 0.f;
    const float* sb = support + (size_t)b * NS * DIM + qd * 1024;
    for (int cc = 0; cc < 8; cc++) {
        __syncthreads();
        for (int idx = tid; idx < 80 * 32; idx += 256) {
            int r = idx >> 5, d4 = idx & 31;
            float4 v = make_float4(0.f, 0.f, 0.f, 0.f);
            if (r < 75) v = *(const float4*)&sb[(size_t)r * DIM + cc * 128 + d4 * 4];
            *(float4*)&Ss[r * 132 + d4 * 4] = v;
        }
        __syncthreads();
        for (int d4 = 0; d4 < 32; d4++) {
            float4 av[5], bv[5];
#pragma unroll
            for (int u = 0; u < 5; u++) av[u] = *(const float4*)&Ss[(ty * 5 + u) * 132 + d4 * 4];
#pragma unroll
            for (int v = 0; v < 5; v++) bv[v] = *(const float4*)&Ss[(tx * 5 + v) * 132 + d4 * 4];
#pragma unroll
            for (int u = 0; u < 5; u++)
#pragma unroll
                for (int v = 0; v < 5; v++)
                    acc[u][v] += av[u].x * bv[v].x + av[u].y * bv[v].y +
                                 av[u].z * bv[v].z + av[u].w * bv[v].w;
        }
    }
    float* Ko = Kp + (size_t)(qd * 64 + b) * 5776;
#pragma unroll
    for (int u = 0; u < 5; u++) {
        int row = ty * 5 + u;
#pragma unroll
        for (int v = 0; v < 5; v++) {
            int col = tx * 5 + v;
            if (row < 75 && col < 75) Ko[row * 76 + col] = acc[u][v];
        }
    }
}

// reduce 4 partials into padded Kg (pad row/col 75: identity)
__global__ void gram_reduce(const float* __restrict__ Kp, float* __restrict__ Kg) {
    int idx = blockIdx.x * 256 + threadIdx.x;
    if (idx >= 64 * 5776) return;
    int rc = idx % 5776;
    int row = rc / 76, col = rc % 76;
    float val;
    if (row < 75 && col < 75)
        val = Kp[idx] + Kp[369664 + idx] + Kp[2 * 369664 + idx] + Kp[3 * 369664 + idx];
    else
        val = (row == col) ? 1.f : 0.f;
    Kg[idx] = val;
}

// ---------------- in-place Gauss-Jordan inverse of padded 76x76 (one wave).
// Lane layout: jl = lane&7 owns j4 in {jl, jl+8, jl+16<19}; rl = lane>>3 owns
// rows rl*10..rl*10+9 (<76). Rank-1 sweeps, pivot row kept unscaled during
// elimination (f = M[i][k]*pinv), scaled after. Pad row/col stays identity.
__device__ __forceinline__ void wave_gj76(float* M, float4* M4, int lane) {
    const int jl = lane & 7;
    const int rl = lane >> 3;
    for (int k = 0; k < 75; k++) {
        float pinv = 1.f / M[k * 76 + k];
        float f[10];
#pragma unroll
        for (int r = 0; r < 10; r++) {
            int row = rl * 10 + r;
            f[r] = (row < 76 && row != k) ? M[row * 76 + k] * pinv : 0.f;
        }
        __syncthreads();
#pragma unroll
        for (int t = 0; t < 3; t++) {
            int j4 = jl + 8 * t;
            if (j4 < 19) {
                float4 P = M4[k * 19 + j4];
#pragma unroll
                for (int r = 0; r < 10; r++) {
                    int row = rl * 10 + r;
                    if (row < 76 && row != k) {
                        float4 m = M4[row * 19 + j4];
                        m.x -= f[r] * P.x; m.y -= f[r] * P.y;
                        m.z -= f[r] * P.z; m.w -= f[r] * P.w;
                        M4[row * 19 + j4] = m;
                    }
                }
            }
        }
        __syncthreads();
        if (jl == 0) {
#pragma unroll
            for (int r = 0; r < 10; r++) {
                int row = rl * 10 + r;
                if (row < 76 && row != k) M[row * 76 + k] = -f[r];
            }
        }
        if (lane < 19) {
            float4 v = M4[k * 19 + lane];
            v.x *= pinv; v.y *= pinv; v.z *= pinv; v.w *= pinv;
            if (lane == (k >> 2)) {
                int kq = k & 3;
                if (kq == 0) v.x = pinv; else if (kq == 1) v.y = pinv;
                else if (kq == 2) v.z = pinv; else v.w = pinv;
            }
            M4[k * 19 + lane] = v;
        }
        __syncthreads();
    }
}

// ------------------------------------- per (task, way), ONE WAVE per block:
// residual slice, H_w = K + I + diag(D_w), W = H^-1 via GJ, t = W r1.
__global__ __launch_bounds__(64) void factor_kernel(
        const float* __restrict__ Kg, const int* __restrict__ labels,
        const float* __restrict__ zg, const float* __restrict__ sg,
        const float* __restrict__ lamg, const float* __restrict__ nug,
        float* __restrict__ Wg, float* __restrict__ tv) {
    int w = blockIdx.x, b = blockIdx.y;
    int lane = threadIdx.x;
    __shared__ __align__(16) float Mb[5776];
    __shared__ __align__(16) float zw[80];
    __shared__ __align__(16) float r1w[80];
    float4* M4 = (float4*)Mb;

    const float4* Kt4 = (const float4*)(Kg + (size_t)b * 5776);
    for (int idx = lane; idx < 1444; idx += 64) M4[idx] = Kt4[idx];
    if (lane < 16) { zw[64 + lane] = 0.f; r1w[64 + lane] = 0.f; }

    float svv[2], lvv[2], nuv[2];
#pragma unroll
    for (int o = 0; o < 2; o++) {
        int i = lane + 64 * o;
        if (i < 75) {
            zw[i]  = zg[b * NTOT + i * NW + w];
            svv[o] = sg[b * NTOT + i * NW + w];
            lvv[o] = lamg[b * NTOT + i * NW + w];
            nuv[o] = nug[b * NS + i];
        }
    }
    float part = 0.f;
    for (int idx = lane; idx < NTOT; idx += 64)
        part += lamg[b * NTOT + idx] * sg[b * NTOT + idx];
#pragma unroll
    for (int off = 32; off > 0; off >>= 1) part += __shfl_xor(part, off, 64);
    float mu = part * (1.f / (float)NTOT);
    __syncthreads();

#pragma unroll
    for (int o = 0; o < 2; o++) {
        int i = lane + 64 * o;
        if (i < 75) {
            int labv = labels[b * NS + i];
            float e = (labv == w) ? -1.f : 0.f;
            float h = (labv == w) ? CREG : 0.f;
            const float4* mr = M4 + i * 19;
            const float4* zz = (const float4*)zw;
            float gz = 0.f;
#pragma unroll
            for (int j = 0; j < 19; j++) {
                float4 a = mr[j], z4 = zz[j];
                gz += a.x * z4.x + a.y * z4.y + a.z * z4.z + a.w * z4.w;
            }
            gz += zw[i];                      // + I z
            float rz = gz + e + lvv[o] + nuv[o];
            float rs = zw[i] + svv[o] - h;
            r1w[i] = -rz - (lvv[o] * rs - lvv[o] * svv[o] + SIGMA * mu) / svv[o];
            Mb[i * 76 + i] += 1.f + lvv[o] / svv[o];
        }
    }
    __syncthreads();

    wave_gj76(Mb, M4, lane);

    float4* Wo4 = (float4*)(Wg + (size_t)(b * NW + w) * 5776);
    for (int idx = lane; idx < 1444; idx += 64) Wo4[idx] = M4[idx];
#pragma unroll
    for (int o = 0; o < 2; o++) {
        int i = lane + 64 * o;
        if (i < 75) {
            const float4* mr = M4 + i * 19;
            const float4* rr = (const float4*)r1w;
            float a2 = 0.f;
#pragma unroll
            for (int j = 0; j < 19; j++) {
                float4 x = mr[j], y = rr[j];
                a2 += x.x * y.x + x.y * y.y + x.z * y.z + x.w * y.w;
            }
            tv[(b * NW + w) * 75 + i] = a2;
        }
    }
}

// ------------------------- per task, ONE WAVE: S = sum_w W_w, Sinv via GJ,
// dnu = Sinv*rhs, dz/ds/dlam + step, state update.
__global__ __launch_bounds__(64) void schur_update_kernel(
        const int* __restrict__ labels,
        float* __restrict__ z, float* __restrict__ s,
        float* __restrict__ lam, float* __restrict__ nu,
        const float* __restrict__ Wg, const float* __restrict__ tv) {
    int b = blockIdx.x;
    int lane = threadIdx.x;
    __shared__ __align__(16) float Mb[5776];
    __shared__ __align__(16) float zl[384], sl[384], ll[384], tvl[384];
    __shared__ __align__(16) float rhs[80], dnu[80];
    float4* M4 = (float4*)Mb;

    const float4* Wb4 = (const float4*)(Wg + (size_t)b * NW * 5776);
    for (int idx = lane; idx < 1444; idx += 64) {
        float4 a  = Wb4[idx];
        float4 c1 = Wb4[1444 + idx];
        float4 c2 = Wb4[2888 + idx];
        float4 c3 = Wb4[4332 + idx];
        float4 c4 = Wb4[5776 + idx];
        a.x += c1.x + c2.x + c3.x + c4.x;
        a.y += c1.y + c2.y + c3.y + c4.y;
        a.z += c1.z + c2.z + c3.z + c4.z;
        a.w += c1.w + c2.w + c3.w + c4.w;
        M4[idx] = a;
    }
    for (int idx = lane; idx < NTOT; idx += 64) {
        zl[idx] = z[b * NTOT + idx];
        sl[idx] = s[b * NTOT + idx];
        ll[idx] = lam[b * NTOT + idx];
        int i = idx / 5, ww = idx % 5;
        tvl[idx] = tv[(b * NW + ww) * 75 + i];
    }
    if (lane < 16) { rhs[64 + lane] = 0.f; dnu[64 + lane] = 0.f; }

    float part = 0.f;
    for (int idx = lane; idx < NTOT; idx += 64)
        part += lam[b * NTOT + idx] * s[b * NTOT + idx];
#pragma unroll
    for (int off = 32; off > 0; off >>= 1) part += __shfl_xor(part, off, 64);
    float mu = part * (1.f / (float)NTOT);
    __syncthreads();

#pragma unroll
    for (int o = 0; o < 2; o++) {
        int i = lane + 64 * o;
        if (i < 75) {
            float ra = 0.f, ts = 0.f;
#pragma unroll
            for (int ww = 0; ww < 5; ww++) { ra += zl[i * 5 + ww]; ts += tvl[i * 5 + ww]; }
            rhs[i] = ra + ts;
        }
    }
    __syncthreads();

    wave_gj76(Mb, M4, lane);

#pragma unroll
    for (int o = 0; o < 2; o++) {
        int i = lane + 64 * o;
        if (i < 75) {
            const float4* mr = M4 + i * 19;
            const float4* rr = (const float4*)rhs;
            float a2 = 0.f;
#pragma unroll
            for (int j = 0; j < 19; j++) {
                float4 x = mr[j], y = rr[j];
                a2 += x.x * y.x + x.y * y.y + x.z * y.z + x.w * y.w;
            }
            dnu[i] = a2;
        }
    }
    __syncthreads();

    float rat = INFINITY;
    float dzv[6], dsv[6], dlv[6];
#pragma unroll
    for (int t = 0; t < 6; t++) {
        int c = lane + 64 * t;
        dzv[t] = 0.f; dsv[t] = 0.f; dlv[t] = 0.f;
        if (c < NTOT) {
            int i = c / 5, ww = c % 5;
            const float4* Wr = (const float4*)(Wg + (size_t)(b * NW + ww) * 5776 + i * 76);
            const float4* dn4 = (const float4*)dnu;
            float acc = 0.f;
#pragma unroll
            for (int j = 0; j < 19; j++) {
                float4 x = Wr[j], y = dn4[j];
                acc += x.x * y.x + x.y * y.y + x.z * y.z + x.w * y.w;
            }
            float dz_t = tvl[c] - acc;
            int labv = labels[b * NS + i];
            float h = (labv == ww) ? CREG : 0.f;
            float rs = zl[c] + sl[c] - h;
            float ds_t = -rs - dz_t;
            float dl_t = (ll[c] * dz_t + ll[c] * rs - ll[c] * sl[c] + SIGMA * mu) / sl[c];
            dzv[t] = dz_t; dsv[t] = ds_t; dlv[t] = dl_t;
            float r1 = (ds_t < 0.f) ? (-sl[c] / ds_t) : INFINITY;
            float r2 = (dl_t < 0.f) ? (-ll[c] / dl_t) : INFINITY;
            rat = fminf(rat, fminf(r1, r2));
        }
    }
#pragma unroll
    for (int off = 32; off > 0; off >>= 1) rat = fminf(rat, __shfl_xor(rat, off, 64));
    float alpha = fminf(1.f, 0.99f * rat);
#pragma unroll
    for (int t = 0; t < 6; t++) {
        int c = lane + 64 * t;
        if (c < NTOT) {
            z[b * NTOT + c]   = zl[c] + alpha * dzv[t];
            s[b * NTOT + c]   = sl[c] + alpha * dsv[t];
            lam[b * NTOT + c] = ll[c] + alpha * dlv[t];
        }
    }
#pragma unroll
    for (int o = 0; o < 2; o++) {
        int i = lane + 64 * o;
        if (i < 75) nu[b * NS + i] = nu[b * NS + i] + alpha * dnu[i];
    }
}

// ------------------------------ v[b,w,:] = sum_s z[b,s,w] * support[b,s,:]
__global__ __launch_bounds__(256) void v_kernel(const float* __restrict__ support,
                                                const float* __restrict__ z,
                                                float* __restrict__ vbuf) {
    int dc = blockIdx.x, b = blockIdx.y;
    __shared__ float zs[NTOT];
    int tid = threadIdx.x;
    for (int idx = tid; idx < NTOT; idx += 256) zs[idx] = z[b * NTOT + idx];
    __syncthreads();
    int d = dc * 256 + tid;
    float acc[5] = {0.f, 0.f, 0.f, 0.f, 0.f};
    const float* sb = support + (size_t)b * NS * DIM + d;
    for (int ss = 0; ss < NS; ss++) {
        float svv = sb[(size_t)ss * DIM];
#pragma unroll
        for (int w = 0; w < 5; w++) acc[w] += svv * zs[ss * 5 + w];
    }
#pragma unroll
    for (int w = 0; w < 5; w++) vbuf[(size_t)(b * NW + w) * DIM + d] = acc[w];
}

// -------------------- logits[b,q,w] = sum_d query[b,q,d] * v[b,w,d]
__global__ __launch_bounds__(256) void logits_kernel(const float* __restrict__ query,
                                                     const float* __restrict__ vbuf,
                                                     float* __restrict__ out) {
    int qt = blockIdx.x, b = blockIdx.y;
    __shared__ __align__(16) float vs[5 * 1028];
    int tid = threadIdx.x;
    int lane = tid & 63, wid = tid >> 6;
    float acc[8][5];
#pragma unroll
    for (int r = 0; r < 8; r++)
#pragma unroll
        for (int w = 0; w < 5; w++) acc[r][w] = 0.f;

    for (int c = 0; c < 4; c++) {
        __syncthreads();
        for (int idx = tid; idx < 5120; idx += 256) {
            int w = idx >> 10, dd = idx & 1023;
            vs[w * 1028 + dd] = vbuf[(size_t)(b * NW + w) * DIM + c * 1024 + dd];
        }
        __syncthreads();
#pragma unroll
        for (int ri = 0; ri < 8; ri++) {
            int r = wid + ri * 4;
            if (r < 30) {
                int q = qt * 30 + r;
                const float* qp = query + (size_t)(b * NQ + q) * DIM + c * 1024;
#pragma unroll
                for (int j = 0; j < 4; j++) {
                    int d = lane * 4 + j * 256;
                    float4 qv = *(const float4*)(qp + d);
#pragma unroll
                    for (int w = 0; w < 5; w++) {
                        float4 vv = *(const float4*)(&vs[w * 1028 + d]);
                        acc[ri][w] += qv.x * vv.x + qv.y * vv.y + qv.z * vv.z + qv.w * vv.w;
                    }
                }
            }
        }
    }
#pragma unroll
    for (int ri = 0; ri < 8; ri++) {
        int r = wid + ri * 4;
#pragma unroll
        for (int w = 0; w < 5; w++) {
            float v = acc[ri][w];
            for (int off = 32; off > 0; off >>= 1) v += __shfl_xor(v, off, 64);
            if (r < 30 && lane == 0)
                out[(size_t)(b * NQ + qt * 30 + r) * NW + w] = v;
        }
    }
}

// ---------------------------------------------------------------------------
extern "C" void kernel_launch(void* const* d_in, const int* in_sizes, int n_in,
                              void* d_out, int out_size, void* d_ws, size_t ws_size,
                              hipStream_t stream) {
    const float* query   = (const float*)d_in[0];
    const float* support = (const float*)d_in[1];
    const int*   labels  = (const int*)d_in[2];
    float* out = (float*)d_out;
    float* ws  = (float*)d_ws;

    float* Kg   = ws + OFF_K;
    float* Wg   = ws + OFF_W;
    float* Kp   = ws + OFF_W;   // alias (dead before first factor)
    float* vbuf = ws + OFF_W;   // alias (W dead after last schur)
    float* z    = ws + OFF_Z;
    float* s    = ws + OFF_S;
    float* lam  = ws + OFF_LAM;
    float* nu   = ws + OFF_NU;
    float* tv   = ws + OFF_TV;

    qp_init<<<(T_TASKS * NTOT + 255) / 256, 256, 0, stream>>>(z, s, lam, nu);
    gram_partial<<<dim3(4, T_TASKS), 256, 0, stream>>>(support, Kp);
    gram_reduce<<<(64 * 5776 + 255) / 256, 256, 0, stream>>>(Kp, Kg);
    for (int it = 0; it < QP_ITERS; it++) {
        factor_kernel<<<dim3(NW, T_TASKS), 64, 0, stream>>>(Kg, labels, z, s, lam, nu, Wg, tv);
        schur_update_kernel<<<T_TASKS, 64, 0, stream>>>(labels, z, s, lam, nu, Wg, tv);
    }
    v_kernel<<<dim3(16, T_TASKS), 256, 0, stream>>>(support, z, vbuf);
    logits_kernel<<<dim3(5, T_TASKS), 256, 0, stream>>>(query, vbuf, out);
}

// Round 4
// 2164.151 us; speedup vs baseline: 2.7921x; 2.7921x over previous
//
#include <hip/hip_runtime.h>
#include <math.h>

#define T_TASKS 64
#define NS 75
#define NW 5
#define NTOT 375
#define NQ 150
#define DIM 4096
#define QP_ITERS 15
#define SIGMA 0.1f
#define CREG 0.1f

// workspace layout (float offsets). K padded 76x76 (5776/task).
// W in register-tile layout: per (b,w) 6400 floats, [(m*5+n)*256 + tid].
// Kp (gram partials, 4*369664) and vbuf (1310720) alias the W region.
// Total 2,520,064 floats = 10.1 MB.
#define OFF_K   0u
#define OFF_W   369664u
#define OFF_Z   2417664u
#define OFF_S   2441664u
#define OFF_LAM 2465664u
#define OFF_NU  2489664u
#define OFF_TV  2494464u   // 320*80

// ---------------------------------------------------------------- init state
__global__ void qp_init(float* __restrict__ z, float* __restrict__ s,
                        float* __restrict__ lam, float* __restrict__ nu) {
    int idx = blockIdx.x * 256 + threadIdx.x;
    if (idx < T_TASKS * NTOT) { z[idx] = 0.f; s[idx] = 1.f; lam[idx] = 1.f; }
    if (idx < T_TASKS * NS) nu[idx] = 0.f;
}

// ------------------------------------------- K partial over a d-quarter.
__global__ __launch_bounds__(256) void gram_partial(const float* __restrict__ support,
                                                    float* __restrict__ Kp) {
    int qd = blockIdx.x, b = blockIdx.y;
    __shared__ __align__(16) float Ss[80 * 132];
    int tid = threadIdx.x;
    int tx = tid & 15, ty = tid >> 4;
    float acc[5][5];
#pragma unroll
    for (int u = 0; u < 5; u++)
#pragma unroll
        for (int v = 0; v < 5; v++) acc[u][v] = 0.f;
    const float* sb = support + (size_t)b * NS * DIM + qd * 1024;
    for (int cc = 0; cc < 8; cc++) {
        __syncthreads();
        for (int idx = tid; idx < 80 * 32; idx += 256) {
            int r = idx >> 5, d4 = idx & 31;
            float4 v = make_float4(0.f, 0.f, 0.f, 0.f);
            if (r < 75) v = *(const float4*)&sb[(size_t)r * DIM + cc * 128 + d4 * 4];
            *(float4*)&Ss[r * 132 + d4 * 4] = v;
        }
        __syncthreads();
        for (int d4 = 0; d4 < 32; d4++) {
            float4 av[5], bv[5];
#pragma unroll
            for (int u = 0; u < 5; u++) av[u] = *(const float4*)&Ss[(ty * 5 + u) * 132 + d4 * 4];
#pragma unroll
            for (int v = 0; v < 5; v++) bv[v] = *(const float4*)&Ss[(tx * 5 + v) * 132 + d4 * 4];
#pragma unroll
            for (int u = 0; u < 5; u++)
#pragma unroll
                for (int v = 0; v < 5; v++)
                    acc[u][v] += av[u].x * bv[v].x + av[u].y * bv[v].y +
                                 av[u].z * bv[v].z + av[u].w * bv[v].w;
        }
    }
    float* Ko = Kp + (size_t)(qd * 64 + b) * 5776;
#pragma unroll
    for (int u = 0; u < 5; u++) {
        int row = ty * 5 + u;
#pragma unroll
        for (int v = 0; v < 5; v++) {
            int col = tx * 5 + v;
            if (row < 75 && col < 75) Ko[row * 76 + col] = acc[u][v];
        }
    }
}

// reduce 4 partials into padded Kg (pad row/col >=75: identity)
__global__ void gram_reduce(const float* __restrict__ Kp, float* __restrict__ Kg) {
    int idx = blockIdx.x * 256 + threadIdx.x;
    if (idx >= 64 * 5776) return;
    int rc = idx % 5776;
    int row = rc / 76, col = rc % 76;
    float val;
    if (row < 75 && col < 75)
        val = Kp[idx] + Kp[369664 + idx] + Kp[2 * 369664 + idx] + Kp[3 * 369664 + idx];
    else
        val = (row == col) ? 1.f : 0.f;
    Kg[idx] = val;
}

// --------------- register-resident Gauss-Jordan inverse of 80x80 (pad>=76 I,
// pad 75 I from Kg). Thread (ty,tx) owns rows {ty+16m} x cols {tx+16n} in
// M[5][5] (VGPRs). Per step: pivot row/col broadcast through double-buffered
// LDS (one barrier per k), rank-1 update in registers. Pivots k<75 only.
__device__ __forceinline__ void reg_gj80(float (&M)[5][5],
                                         float (*prow)[80], float (*fcol)[80],
                                         int tx, int ty) {
    for (int k = 0; k < 75; k++) {
        int bf = k & 1;
        if (ty == (k & 15)) {
#pragma unroll
            for (int m = 0; m < 5; m++) {
                if (ty + 16 * m == k) {
#pragma unroll
                    for (int n = 0; n < 5; n++) prow[bf][tx + 16 * n] = M[m][n];
                }
            }
        }
        if (tx == (k & 15)) {
#pragma unroll
            for (int n = 0; n < 5; n++) {
                if (tx + 16 * n == k) {
#pragma unroll
                    for (int m = 0; m < 5; m++) fcol[bf][ty + 16 * m] = M[m][n];
                }
            }
        }
        __syncthreads();
        float pinv = 1.f / prow[bf][k];
        float pv[5], fv[5], ps[5];
#pragma unroll
        for (int n = 0; n < 5; n++) {
            pv[n] = prow[bf][tx + 16 * n];
            ps[n] = pv[n] * pinv;
        }
#pragma unroll
        for (int m = 0; m < 5; m++) {
            int r = ty + 16 * m;
            float f = fcol[bf][r] * pinv;
            fv[m] = (r == k) ? 0.f : f;
        }
#pragma unroll
        for (int m = 0; m < 5; m++) {
            int r = ty + 16 * m;
            bool rk = (r == k);
#pragma unroll
            for (int n = 0; n < 5; n++) {
                int c = tx + 16 * n;
                float val = M[m][n] - fv[m] * pv[n];
                val = rk ? ps[n] : val;
                val = (c == k) ? (rk ? pinv : -fv[m]) : val;
                M[m][n] = val;
            }
        }
    }
}

// ------------------------------------- per (task, way), 256 threads:
// residuals, H_w = K + I + diag(D_w) in registers, W = H^-1 via reg-GJ,
// W -> global (tile layout, coalesced), t = W r1.
__global__ __launch_bounds__(256) void factor_kernel(
        const float* __restrict__ Kg, const int* __restrict__ labels,
        const float* __restrict__ zg, const float* __restrict__ sg,
        const float* __restrict__ lamg, const float* __restrict__ nug,
        float* __restrict__ Wg, float* __restrict__ tvg) {
    int w = blockIdx.x, b = blockIdx.y;
    int tid = threadIdx.x;
    int tx = tid & 15, ty = tid >> 4;
    __shared__ float prow[2][80], fcol[2][80];
    __shared__ float zw[80], r1w[80], Dv[80], swv[80], lwv[80], nuwv[80];
    __shared__ int labv[80];
    __shared__ float mred[4];

    float M[5][5];
    const float* Kt = Kg + (size_t)b * 5776;
#pragma unroll
    for (int m = 0; m < 5; m++) {
        int r = ty + 16 * m;
#pragma unroll
        for (int n = 0; n < 5; n++) {
            int c = tx + 16 * n;
            M[m][n] = (r < 76 && c < 76) ? Kt[r * 76 + c] : ((r == c) ? 1.f : 0.f);
        }
    }
    if (tid < 80) {
        float zv = 0.f, sv = 1.f, lv = 0.f, nv = 0.f; int lb = -1;
        if (tid < 75) {
            zv = zg[b * NTOT + tid * NW + w];
            sv = sg[b * NTOT + tid * NW + w];
            lv = lamg[b * NTOT + tid * NW + w];
            nv = nug[b * NS + tid];
            lb = labels[b * NS + tid];
        }
        zw[tid] = zv; swv[tid] = sv; lwv[tid] = lv; nuwv[tid] = nv; labv[tid] = lb;
    }
    float part = 0.f;
    for (int idx = tid; idx < NTOT; idx += 256)
        part += lamg[b * NTOT + idx] * sg[b * NTOT + idx];
#pragma unroll
    for (int off = 32; off > 0; off >>= 1) part += __shfl_xor(part, off, 64);
    if ((tid & 63) == 0) mred[tid >> 6] = part;
    __syncthreads();
    float mu = (mred[0] + mred[1] + mred[2] + mred[3]) * (1.f / (float)NTOT);

    // gz = K z (row dots via register tile + tx-reduction)
    float gp[5];
#pragma unroll
    for (int m = 0; m < 5; m++) {
        float a = 0.f;
#pragma unroll
        for (int n = 0; n < 5; n++) a += M[m][n] * zw[tx + 16 * n];
        gp[m] = a;
    }
#pragma unroll
    for (int off = 1; off < 16; off <<= 1)
#pragma unroll
        for (int m = 0; m < 5; m++) gp[m] += __shfl_xor(gp[m], off, 64);
    if (tx == 0) {
#pragma unroll
        for (int m = 0; m < 5; m++) {
            int r = ty + 16 * m;
            float val = 0.f, dv = 0.f;
            if (r < 75) {
                float sv = swv[r], lv = lwv[r], zv = zw[r];
                float e = (labv[r] == w) ? -1.f : 0.f;
                float h = (labv[r] == w) ? CREG : 0.f;
                float rz = gp[m] + zv + e + lv + nuwv[r];
                float rs = zv + sv - h;
                val = -rz - (lv * rs - lv * sv + SIGMA * mu) / sv;
                dv = lv / sv;
            }
            r1w[r] = val; Dv[r] = dv;
        }
    }
    __syncthreads();
    if (tx == ty) {
#pragma unroll
        for (int m = 0; m < 5; m++) {
            int r = ty + 16 * m;
            if (r < 75) M[m][m] += 1.f + Dv[r];
        }
    }
    // (no barrier needed: registers are private; GJ's internal barrier orders LDS)

    reg_gj80(M, prow, fcol, tx, ty);

    // W out, tile layout: fully coalesced
    float* Wo = Wg + (size_t)(b * NW + w) * 6400;
#pragma unroll
    for (int m = 0; m < 5; m++)
#pragma unroll
        for (int n = 0; n < 5; n++)
            Wo[(m * 5 + n) * 256 + tid] = M[m][n];

    // t = W r1
    float tp[5];
#pragma unroll
    for (int m = 0; m < 5; m++) {
        float a = 0.f;
#pragma unroll
        for (int n = 0; n < 5; n++) a += M[m][n] * r1w[tx + 16 * n];
        tp[m] = a;
    }
#pragma unroll
    for (int off = 1; off < 16; off <<= 1)
#pragma unroll
        for (int m = 0; m < 5; m++) tp[m] += __shfl_xor(tp[m], off, 64);
    if (tx == 0) {
#pragma unroll
        for (int m = 0; m < 5; m++) {
            int r = ty + 16 * m;
            if (r < 75) tvg[(b * NW + w) * 80 + r] = tp[m];
        }
    }
}

// ------------------------- per task, 256 threads: S = sum_w W_w (registers,
// coalesced), Sinv via reg-GJ, dnu, dz/ds/dlam + step, state update.
__global__ __launch_bounds__(256) void schur_update_kernel(
        const int* __restrict__ labels,
        float* __restrict__ z, float* __restrict__ s,
        float* __restrict__ lam, float* __restrict__ nu,
        const float* __restrict__ Wg, const float* __restrict__ tvg) {
    int b = blockIdx.x;
    int tid = threadIdx.x;
    int tx = tid & 15, ty = tid >> 4;
    __shared__ float prow[2][80], fcol[2][80];
    __shared__ __align__(16) float rhs[80];
    __shared__ __align__(16) float dnu[80];
    __shared__ float mred[4], ared[4];

    float M[5][5];
    const float* Wb = Wg + (size_t)b * NW * 6400;
#pragma unroll
    for (int m = 0; m < 5; m++)
#pragma unroll
        for (int n = 0; n < 5; n++) {
            float a = 0.f;
#pragma unroll
            for (int ww = 0; ww < 5; ww++)
                a += Wb[ww * 6400 + (m * 5 + n) * 256 + tid];
            M[m][n] = a;
        }
    if (tid < 80) {
        float rv = 0.f;
        if (tid < 75) {
#pragma unroll
            for (int ww = 0; ww < 5; ww++)
                rv += z[b * NTOT + tid * NW + ww] + tvg[(b * NW + ww) * 80 + tid];
        }
        rhs[tid] = rv;
    }
    float part = 0.f;
    for (int idx = tid; idx < NTOT; idx += 256)
        part += lam[b * NTOT + idx] * s[b * NTOT + idx];
#pragma unroll
    for (int off = 32; off > 0; off >>= 1) part += __shfl_xor(part, off, 64);
    if ((tid & 63) == 0) mred[tid >> 6] = part;
    __syncthreads();
    float mu = (mred[0] + mred[1] + mred[2] + mred[3]) * (1.f / (float)NTOT);

    reg_gj80(M, prow, fcol, tx, ty);   // M = S^{-1}

    // dnu = Sinv * rhs
    float tp[5];
#pragma unroll
    for (int m = 0; m < 5; m++) {
        float a = 0.f;
#pragma unroll
        for (int n = 0; n < 5; n++) a += M[m][n] * rhs[tx + 16 * n];
        tp[m] = a;
    }
#pragma unroll
    for (int off = 1; off < 16; off <<= 1)
#pragma unroll
        for (int m = 0; m < 5; m++) tp[m] += __shfl_xor(tp[m], off, 64);
    if (tx == 0) {
#pragma unroll
        for (int m = 0; m < 5; m++) dnu[ty + 16 * m] = tp[m];
    }
    __syncthreads();

    // dz/ds/dlam + ratio; entries c = tid, tid+256
    float rat = INFINITY;
    float dzv[2], dsv[2], dlv[2], zlv[2], slv[2], llv[2];
#pragma unroll
    for (int pass = 0; pass < 2; pass++) {
        int c = tid + 256 * pass;
        dzv[pass] = 0.f; dsv[pass] = 0.f; dlv[pass] = 0.f;
        zlv[pass] = 0.f; slv[pass] = 1.f; llv[pass] = 0.f;
        if (c < NTOT) {
            int i = c / 5, ww = c - (c / 5) * 5;
            int mi = i >> 4, tyi = i & 15;
            const float* Wr = Wb + ww * 6400 + mi * 5 * 256 + tyi * 16;
            const float4* dn4 = (const float4*)dnu;
            float acc = 0.f;
#pragma unroll
            for (int n = 0; n < 5; n++) {
                const float4* w4 = (const float4*)(Wr + n * 256);
#pragma unroll
                for (int q = 0; q < 4; q++) {
                    float4 x = w4[q], y = dn4[4 * n + q];
                    acc += x.x * y.x + x.y * y.y + x.z * y.z + x.w * y.w;
                }
            }
            float tvl = tvg[(b * NW + ww) * 80 + i];
            float zl = z[b * NTOT + c], sl = s[b * NTOT + c], ll = lam[b * NTOT + c];
            float dz_t = tvl - acc;
            int lb = labels[b * NS + i];
            float h = (lb == ww) ? CREG : 0.f;
            float rs = zl + sl - h;
            float ds_t = -rs - dz_t;
            float dl_t = (ll * dz_t + ll * rs - ll * sl + SIGMA * mu) / sl;
            zlv[pass] = zl; slv[pass] = sl; llv[pass] = ll;
            dzv[pass] = dz_t; dsv[pass] = ds_t; dlv[pass] = dl_t;
            float r1 = (ds_t < 0.f) ? (-sl / ds_t) : INFINITY;
            float r2 = (dl_t < 0.f) ? (-ll / dl_t) : INFINITY;
            rat = fminf(rat, fminf(r1, r2));
        }
    }
#pragma unroll
    for (int off = 32; off > 0; off >>= 1) rat = fminf(rat, __shfl_xor(rat, off, 64));
    if ((tid & 63) == 0) ared[tid >> 6] = rat;
    __syncthreads();
    float alpha = fminf(1.f, 0.99f * fminf(fminf(ared[0], ared[1]), fminf(ared[2], ared[3])));
#pragma unroll
    for (int pass = 0; pass < 2; pass++) {
        int c = tid + 256 * pass;
        if (c < NTOT) {
            z[b * NTOT + c]   = zlv[pass] + alpha * dzv[pass];
            s[b * NTOT + c]   = slv[pass] + alpha * dsv[pass];
            lam[b * NTOT + c] = llv[pass] + alpha * dlv[pass];
        }
    }
    if (tid < 75) nu[b * NS + tid] += alpha * dnu[tid];
}

// ------------------------------ v[b,w,:] = sum_s z[b,s,w] * support[b,s,:]
__global__ __launch_bounds__(256) void v_kernel(const float* __restrict__ support,
                                                const float* __restrict__ z,
                                                float* __restrict__ vbuf) {
    int dc = blockIdx.x, b = blockIdx.y;
    __shared__ float zs[NTOT];
    int tid = threadIdx.x;
    for (int idx = tid; idx < NTOT; idx += 256) zs[idx] = z[b * NTOT + idx];
    __syncthreads();
    int d = dc * 256 + tid;
    float acc[5] = {0.f, 0.f, 0.f, 0.f, 0.f};
    const float* sb = support + (size_t)b * NS * DIM + d;
    for (int ss = 0; ss < NS; ss++) {
        float svv = sb[(size_t)ss * DIM];
#pragma unroll
        for (int w = 0; w < 5; w++) acc[w] += svv * zs[ss * 5 + w];
    }
#pragma unroll
    for (int w = 0; w < 5; w++) vbuf[(size_t)(b * NW + w) * DIM + d] = acc[w];
}

// -------------------- logits[b,q,w] = sum_d query[b,q,d] * v[b,w,d]
__global__ __launch_bounds__(256) void logits_kernel(const float* __restrict__ query,
                                                     const float* __restrict__ vbuf,
                                                     float* __restrict__ out) {
    int qt = blockIdx.x, b = blockIdx.y;
    __shared__ __align__(16) float vs[5 * 1028];
    int tid = threadIdx.x;
    int lane = tid & 63, wid = tid >> 6;
    float acc[8][5];
#pragma unroll
    for (int r = 0; r < 8; r++)
#pragma unroll
        for (int w = 0; w < 5; w++) acc[r][w] = 0.f;

    for (int c = 0; c < 4; c++) {
        __syncthreads();
        for (int idx = tid; idx < 5120; idx += 256) {
            int w = idx >> 10, dd = idx & 1023;
            vs[w * 1028 + dd] = vbuf[(size_t)(b * NW + w) * DIM + c * 1024 + dd];
        }
        __syncthreads();
#pragma unroll
        for (int ri = 0; ri < 8; ri++) {
            int r = wid + ri * 4;
            if (r < 30) {
                int q = qt * 30 + r;
                const float* qp = query + (size_t)(b * NQ + q) * DIM + c * 1024;
#pragma unroll
                for (int j = 0; j < 4; j++) {
                    int d = lane * 4 + j * 256;
                    float4 qv = *(const float4*)(qp + d);
#pragma unroll
                    for (int w = 0; w < 5; w++) {
                        float4 vv = *(const float4*)(&vs[w * 1028 + d]);
                        acc[ri][w] += qv.x * vv.x + qv.y * vv.y + qv.z * vv.z + qv.w * vv.w;
                    }
                }
            }
        }
    }
#pragma unroll
    for (int ri = 0; ri < 8; ri++) {
        int r = wid + ri * 4;
#pragma unroll
        for (int w = 0; w < 5; w++) {
            float v = acc[ri][w];
            for (int off = 32; off > 0; off >>= 1) v += __shfl_xor(v, off, 64);
            if (r < 30 && lane == 0)
                out[(size_t)(b * NQ + qt * 30 + r) * NW + w] = v;
        }
    }
}

// ---------------------------------------------------------------------------
extern "C" void kernel_launch(void* const* d_in, const int* in_sizes, int n_in,
                              void* d_out, int out_size, void* d_ws, size_t ws_size,
                              hipStream_t stream) {
    const float* query   = (const float*)d_in[0];
    const float* support = (const float*)d_in[1];
    const int*   labels  = (const int*)d_in[2];
    float* out = (float*)d_out;
    float* ws  = (float*)d_ws;

    float* Kg   = ws + OFF_K;
    float* Wg   = ws + OFF_W;
    float* Kp   = ws + OFF_W;   // alias (dead before first factor)
    float* vbuf = ws + OFF_W;   // alias (W dead after last schur)
    float* z    = ws + OFF_Z;
    float* s    = ws + OFF_S;
    float* lam  = ws + OFF_LAM;
    float* nu   = ws + OFF_NU;
    float* tv   = ws + OFF_TV;

    qp_init<<<(T_TASKS * NTOT + 255) / 256, 256, 0, stream>>>(z, s, lam, nu);
    gram_partial<<<dim3(4, T_TASKS), 256, 0, stream>>>(support, Kp);
    gram_reduce<<<(64 * 5776 + 255) / 256, 256, 0, stream>>>(Kp, Kg);
    for (int it = 0; it < QP_ITERS; it++) {
        factor_kernel<<<dim3(NW, T_TASKS), 256, 0, stream>>>(Kg, labels, z, s, lam, nu, Wg, tv);
        schur_update_kernel<<<T_TASKS, 256, 0, stream>>>(labels, z, s, lam, nu, Wg, tv);
    }
    v_kernel<<<dim3(16, T_TASKS), 256, 0, stream>>>(support, z, vbuf);
    logits_kernel<<<dim3(5, T_TASKS), 256, 0, stream>>>(query, vbuf, out);
}